// Round 1
// baseline (106.053 us; speedup 1.0000x reference)
//
#include <hip/hip_runtime.h>
#include <math.h>

// Problem sizes (fixed by setup_inputs): B=4, N=512, M=512, D=256
#define BB 4
#define NN 512
#define MM 512
#define DD 256
#define RT 8   // rows per block in projection kernels
#define NT 8   // n-rows per block in main kernel

// qs[b*N+n] = sum_e Wr[e] * tanh( sum_d x[b,n,d]*Wq[e,d] + bq[e] )
__global__ __launch_bounds__(256) void k_qs(const float* __restrict__ x,
    const float* __restrict__ Wq, const float* __restrict__ bq,
    const float* __restrict__ Wr, float* __restrict__ qs)
{
    __shared__ float xs[RT][DD];
    __shared__ float red[RT][4];
    const int e = threadIdx.x;
    const int row0 = blockIdx.x * RT;
    #pragma unroll
    for (int j = 0; j < RT; ++j) xs[j][e] = x[(size_t)(row0 + j) * DD + e];
    __syncthreads();
    float acc[RT];
    const float b0 = bq[e];
    #pragma unroll
    for (int j = 0; j < RT; ++j) acc[j] = b0;
    const float* __restrict__ wrow = Wq + (size_t)e * DD;
    #pragma unroll 4
    for (int d = 0; d < DD; ++d) {
        const float wv = wrow[d];
        #pragma unroll
        for (int j = 0; j < RT; ++j) acc[j] = fmaf(xs[j][d], wv, acc[j]);
    }
    const float wr = Wr[e];
    const int lane = e & 63, wave = e >> 6;
    #pragma unroll
    for (int j = 0; j < RT; ++j) {
        float p = wr * tanhf(acc[j]);
        #pragma unroll
        for (int off = 32; off; off >>= 1) p += __shfl_xor(p, off);
        if (lane == 0) red[j][wave] = p;
    }
    __syncthreads();
    if (e < RT) qs[row0 + e] = red[e][0] + red[e][1] + red[e][2] + red[e][3];
}

// ks[b*M+m] = sum_e Wr[e]*tanh(sum_d c[b,m,d]*Wk[e,d])
// v[b,m,e]  = (sum_d c[b,m,d]*Wv[e,d] + bv[e]) * (1/16)
__global__ __launch_bounds__(256) void k_ksv(const float* __restrict__ c,
    const float* __restrict__ Wk, const float* __restrict__ Wr,
    const float* __restrict__ Wv, const float* __restrict__ bv,
    float* __restrict__ ks, float* __restrict__ v)
{
    __shared__ float cs[RT][DD];
    __shared__ float red[RT][4];
    const int e = threadIdx.x;
    const int row0 = blockIdx.x * RT;
    #pragma unroll
    for (int j = 0; j < RT; ++j) cs[j][e] = c[(size_t)(row0 + j) * DD + e];
    __syncthreads();
    float ak[RT], av[RT];
    const float b0 = bv[e];
    #pragma unroll
    for (int j = 0; j < RT; ++j) { ak[j] = 0.0f; av[j] = b0; }
    const float* __restrict__ wkr = Wk + (size_t)e * DD;
    const float* __restrict__ wvr = Wv + (size_t)e * DD;
    #pragma unroll 4
    for (int d = 0; d < DD; ++d) {
        const float a = wkr[d];
        const float w = wvr[d];
        #pragma unroll
        for (int j = 0; j < RT; ++j) {
            const float cv = cs[j][d];
            ak[j] = fmaf(cv, a, ak[j]);
            av[j] = fmaf(cv, w, av[j]);
        }
    }
    #pragma unroll
    for (int j = 0; j < RT; ++j)
        v[(size_t)(row0 + j) * DD + e] = av[j] * 0.0625f;  // 1/sqrt(256)
    const float wr = Wr[e];
    const int lane = e & 63, wave = e >> 6;
    #pragma unroll
    for (int j = 0; j < RT; ++j) {
        float p = wr * tanhf(ak[j]);
        #pragma unroll
        for (int off = 32; off; off >>= 1) p += __shfl_xor(p, off);
        if (lane == 0) red[j][wave] = p;
    }
    __syncthreads();
    if (e < RT) ks[row0 + e] = red[e][0] + red[e][1] + red[e][2] + red[e][3];
}

// out[b,n,:] = LN( x[b,n,:] + sum_m relu(tanh(qs+ks))*mask * v[b,m,:] )
__global__ __launch_bounds__(256) void k_main(const float* __restrict__ x,
    const float* __restrict__ mask, const float* __restrict__ qs,
    const float* __restrict__ ks, const float* __restrict__ v,
    const float* __restrict__ gamma, const float* __restrict__ beta,
    float* __restrict__ out)
{
    __shared__ float w[NT][MM];
    __shared__ float ksm[MM];
    __shared__ float rs[NT][4], rs2[NT][4];
    const int tid = threadIdx.x;
    const int ntiles = NN / NT;  // 64
    const int b = blockIdx.x / ntiles;
    const int n0 = (blockIdx.x % ntiles) * NT;

    for (int m = tid; m < MM; m += 256) ksm[m] = ks[b * MM + m];
    __syncthreads();

    #pragma unroll
    for (int j = 0; j < NT; ++j) {
        const float q = qs[b * NN + n0 + j];
        const float* __restrict__ mrow = mask + ((size_t)(b * NN + n0 + j)) * MM;
        for (int m = tid; m < MM; m += 256) {
            float s = tanhf(q + ksm[m]);
            s = fmaxf(s, 0.0f);
            w[j][m] = s * mrow[m];
        }
    }
    __syncthreads();

    float acc[NT];
    #pragma unroll
    for (int j = 0; j < NT; ++j) acc[j] = 0.0f;
    const float* __restrict__ vb = v + (size_t)b * MM * DD + tid;
    #pragma unroll 4
    for (int m = 0; m < MM; ++m) {
        const float vv = vb[(size_t)m * DD];
        #pragma unroll
        for (int j = 0; j < NT; ++j) acc[j] = fmaf(w[j][m], vv, acc[j]);
    }

    // residual + LayerNorm epilogue
    const int lane = tid & 63, wave = tid >> 6;
    float h[NT];
    #pragma unroll
    for (int j = 0; j < NT; ++j) {
        h[j] = x[((size_t)(b * NN + n0 + j)) * DD + tid] + acc[j];
        float s = h[j], s2 = h[j] * h[j];
        #pragma unroll
        for (int off = 32; off; off >>= 1) {
            s  += __shfl_xor(s, off);
            s2 += __shfl_xor(s2, off);
        }
        if (lane == 0) { rs[j][wave] = s; rs2[j][wave] = s2; }
    }
    __syncthreads();
    const float g = gamma[tid], bt = beta[tid];
    #pragma unroll
    for (int j = 0; j < NT; ++j) {
        const float ts  = rs[j][0] + rs[j][1] + rs[j][2] + rs[j][3];
        const float ts2 = rs2[j][0] + rs2[j][1] + rs2[j][2] + rs2[j][3];
        const float mean = ts * (1.0f / DD);
        const float var  = ts2 * (1.0f / DD) - mean * mean;
        const float inv  = rsqrtf(var + 1e-5f);
        out[((size_t)(b * NN + n0 + j)) * DD + tid] = (h[j] - mean) * inv * g + bt;
    }
}

extern "C" void kernel_launch(void* const* d_in, const int* in_sizes, int n_in,
                              void* d_out, int out_size, void* d_ws, size_t ws_size,
                              hipStream_t stream) {
    const float* x     = (const float*)d_in[0];
    const float* c     = (const float*)d_in[1];
    const float* mask  = (const float*)d_in[2];
    const float* Wq    = (const float*)d_in[3];
    const float* bq    = (const float*)d_in[4];
    const float* Wk    = (const float*)d_in[5];
    const float* Wr    = (const float*)d_in[6];
    const float* Wv    = (const float*)d_in[7];
    const float* bv    = (const float*)d_in[8];
    const float* gamma = (const float*)d_in[9];
    const float* beta  = (const float*)d_in[10];
    float* out = (float*)d_out;

    float* ws    = (float*)d_ws;
    float* qs    = ws;                 // B*N = 2048 floats
    float* ksbuf = ws + BB * NN;       // B*M = 2048 floats
    float* vbuf  = ws + BB * NN + BB * MM;  // B*M*D = 524288 floats

    k_qs <<<(BB * NN) / RT, 256, 0, stream>>>(x, Wq, bq, Wr, qs);
    k_ksv<<<(BB * MM) / RT, 256, 0, stream>>>(c, Wk, Wr, Wv, bv, ksbuf, vbuf);
    k_main<<<(BB * NN) / NT, 256, 0, stream>>>(x, mask, qs, ksbuf, vbuf, gamma, beta, out);
}

// Round 2
// 53.428 us; speedup vs baseline: 1.9850x; 1.9850x over previous
//
#include <hip/hip_runtime.h>
#include <math.h>

// Problem sizes (fixed by setup_inputs): B=4, N=512, M=512, D=256
#define BB 4
#define NN 512
#define MM 512
#define DD 256
#define RT 8    // rows per block in projection kernel
#define NT2 4   // n-rows per block in main kernel (== waves per block)

// Combined projection kernel, 512 blocks:
//   blocks [0,256):   qs[b*N+n] = sum_e Wr[e] * tanh( x[row]·Wq[e,:] + bq[e] )
//   blocks [256,512): ks[b*M+m] = sum_e Wr[e] * tanh( c[row]·Wk[e,:] )
//                     v[row,e]  = (c[row]·Wv[e,:] + bv[e]) / 16
__global__ __launch_bounds__(256) void k_proj(
    const float* __restrict__ x, const float* __restrict__ c,
    const float* __restrict__ Wq, const float* __restrict__ bq,
    const float* __restrict__ Wk, const float* __restrict__ Wr,
    const float* __restrict__ Wv, const float* __restrict__ bv,
    float* __restrict__ qs, float* __restrict__ ks, float* __restrict__ v)
{
    __shared__ float4 sin4[RT][DD / 4];   // 8 KB staged input rows
    __shared__ float red[RT][4];
    const int e = threadIdx.x;
    const int isk = blockIdx.x >> 8;              // 0 = qs half, 1 = ksv half
    const int row0 = (blockIdx.x & 255) * RT;
    const float* __restrict__ src = isk ? c : x;

    // stage RT rows (RT*64 = 512 float4, 2 iters over 256 threads, coalesced)
    {
        const float4* s4 = (const float4*)(src + (size_t)row0 * DD);
        #pragma unroll
        for (int i = 0; i < 2; ++i) {
            const int idx = e + i * 256;
            sin4[idx >> 6][idx & 63] = s4[idx];
        }
    }
    __syncthreads();

    const int lane = e & 63, wave = e >> 6;
    if (!isk) {
        float acc[RT];
        const float b0 = bq[e];
        #pragma unroll
        for (int j = 0; j < RT; ++j) acc[j] = b0;
        const float4* __restrict__ w4 = (const float4*)(Wq + (size_t)e * DD);
        #pragma unroll 4
        for (int d4 = 0; d4 < DD / 4; ++d4) {
            const float4 wq = w4[d4];
            #pragma unroll
            for (int j = 0; j < RT; ++j) {
                const float4 xv = sin4[j][d4];
                acc[j] = fmaf(xv.x, wq.x, acc[j]);
                acc[j] = fmaf(xv.y, wq.y, acc[j]);
                acc[j] = fmaf(xv.z, wq.z, acc[j]);
                acc[j] = fmaf(xv.w, wq.w, acc[j]);
            }
        }
        const float wr = Wr[e];
        #pragma unroll
        for (int j = 0; j < RT; ++j) {
            float p = wr * tanhf(acc[j]);
            #pragma unroll
            for (int off = 32; off; off >>= 1) p += __shfl_xor(p, off);
            if (lane == 0) red[j][wave] = p;
        }
        __syncthreads();
        if (e < RT) qs[row0 + e] = red[e][0] + red[e][1] + red[e][2] + red[e][3];
    } else {
        float ak[RT], av[RT];
        const float b0 = bv[e];
        #pragma unroll
        for (int j = 0; j < RT; ++j) { ak[j] = 0.0f; av[j] = b0; }
        const float4* __restrict__ wk4 = (const float4*)(Wk + (size_t)e * DD);
        const float4* __restrict__ wv4 = (const float4*)(Wv + (size_t)e * DD);
        #pragma unroll 4
        for (int d4 = 0; d4 < DD / 4; ++d4) {
            const float4 a = wk4[d4];
            const float4 w = wv4[d4];
            #pragma unroll
            for (int j = 0; j < RT; ++j) {
                const float4 cv = sin4[j][d4];
                ak[j] = fmaf(cv.x, a.x, ak[j]);
                ak[j] = fmaf(cv.y, a.y, ak[j]);
                ak[j] = fmaf(cv.z, a.z, ak[j]);
                ak[j] = fmaf(cv.w, a.w, ak[j]);
                av[j] = fmaf(cv.x, w.x, av[j]);
                av[j] = fmaf(cv.y, w.y, av[j]);
                av[j] = fmaf(cv.z, w.z, av[j]);
                av[j] = fmaf(cv.w, w.w, av[j]);
            }
        }
        #pragma unroll
        for (int j = 0; j < RT; ++j)
            v[(size_t)(row0 + j) * DD + e] = av[j] * 0.0625f;  // 1/sqrt(256)
        const float wr = Wr[e];
        #pragma unroll
        for (int j = 0; j < RT; ++j) {
            float p = wr * tanhf(ak[j]);
            #pragma unroll
            for (int off = 32; off; off >>= 1) p += __shfl_xor(p, off);
            if (lane == 0) red[j][wave] = p;
        }
        __syncthreads();
        if (e < RT) ks[row0 + e] = red[e][0] + red[e][1] + red[e][2] + red[e][3];
    }
}

// out[b,n,:] = LN( x[b,n,:] + sum_m relu(tanh(qs+ks))*mask * v[b,m,:] )
// Block: 256 threads = 4 waves; NT2=4 rows; wave w handles m-chunk [w*128,w*128+128).
// Each lane owns 4 contiguous d (float4). Cross-wave partials reduced in LDS;
// LN for row j done entirely inside wave j.
__global__ __launch_bounds__(256) void k_main(const float* __restrict__ x,
    const float* __restrict__ mask, const float* __restrict__ qs,
    const float* __restrict__ ks, const float* __restrict__ v,
    const float* __restrict__ gamma, const float* __restrict__ beta,
    float* __restrict__ out)
{
    __shared__ float wscT[MM][NT2];        // 8 KB, [m][j] so one b128 read feeds 4 rows
    __shared__ float ksm[MM];              // 2 KB
    __shared__ float red[4][NT2][DD];      // 16 KB cross-wave partials
    const int tid = threadIdx.x;
    const int lane = tid & 63, wv = tid >> 6;
    const int b = blockIdx.x >> 7;         // 128 blocks per batch
    const int n0 = (blockIdx.x & 127) * NT2;

    for (int m = tid; m < MM; m += 256) ksm[m] = ks[b * MM + m];
    __syncthreads();

    #pragma unroll
    for (int j = 0; j < NT2; ++j) {
        const float q = qs[b * NN + n0 + j];
        const float* __restrict__ mrow = mask + ((size_t)(b * NN + n0 + j)) * MM;
        for (int m = tid; m < MM; m += 256)
            wscT[m][j] = fmaxf(tanhf(q + ksm[m]), 0.0f) * mrow[m];
    }
    __syncthreads();

    // PV partial: wave wv covers 128 m values
    float4 acc[NT2];
    #pragma unroll
    for (int j = 0; j < NT2; ++j) acc[j] = make_float4(0.f, 0.f, 0.f, 0.f);
    const float4* __restrict__ vb = (const float4*)(v + (size_t)b * MM * DD) + lane;
    const int m0 = wv * (MM / 4);
    #pragma unroll 4
    for (int mi = 0; mi < MM / 4; ++mi) {
        const int m = m0 + mi;
        const float4 vv = vb[(size_t)m * (DD / 4)];
        const float4 wj = *(const float4*)&wscT[m][0];   // broadcast: all 4 row-scores
        acc[0].x = fmaf(wj.x, vv.x, acc[0].x); acc[0].y = fmaf(wj.x, vv.y, acc[0].y);
        acc[0].z = fmaf(wj.x, vv.z, acc[0].z); acc[0].w = fmaf(wj.x, vv.w, acc[0].w);
        acc[1].x = fmaf(wj.y, vv.x, acc[1].x); acc[1].y = fmaf(wj.y, vv.y, acc[1].y);
        acc[1].z = fmaf(wj.y, vv.z, acc[1].z); acc[1].w = fmaf(wj.y, vv.w, acc[1].w);
        acc[2].x = fmaf(wj.z, vv.x, acc[2].x); acc[2].y = fmaf(wj.z, vv.y, acc[2].y);
        acc[2].z = fmaf(wj.z, vv.z, acc[2].z); acc[2].w = fmaf(wj.z, vv.w, acc[2].w);
        acc[3].x = fmaf(wj.w, vv.x, acc[3].x); acc[3].y = fmaf(wj.w, vv.y, acc[3].y);
        acc[3].z = fmaf(wj.w, vv.z, acc[3].z); acc[3].w = fmaf(wj.w, vv.w, acc[3].w);
    }
    #pragma unroll
    for (int j = 0; j < NT2; ++j)
        *(float4*)&red[wv][j][lane * 4] = acc[j];
    __syncthreads();

    // wave wv owns output row j = wv
    const int row = n0 + wv;
    float4 h = *(const float4*)(x + ((size_t)(b * NN + row)) * DD + lane * 4);
    const float4 p0 = *(const float4*)&red[0][wv][lane * 4];
    const float4 p1 = *(const float4*)&red[1][wv][lane * 4];
    const float4 p2 = *(const float4*)&red[2][wv][lane * 4];
    const float4 p3 = *(const float4*)&red[3][wv][lane * 4];
    h.x += p0.x + p1.x + p2.x + p3.x;
    h.y += p0.y + p1.y + p2.y + p3.y;
    h.z += p0.z + p1.z + p2.z + p3.z;
    h.w += p0.w + p1.w + p2.w + p3.w;

    float s  = h.x + h.y + h.z + h.w;
    float s2 = h.x * h.x + h.y * h.y + h.z * h.z + h.w * h.w;
    #pragma unroll
    for (int off = 32; off; off >>= 1) {
        s  += __shfl_xor(s, off);
        s2 += __shfl_xor(s2, off);
    }
    const float mean = s * (1.0f / DD);
    const float var  = s2 * (1.0f / DD) - mean * mean;
    const float inv  = rsqrtf(var + 1e-5f);
    const float4 g  = ((const float4*)gamma)[lane];
    const float4 bt = ((const float4*)beta)[lane];
    float4 o;
    o.x = (h.x - mean) * inv * g.x + bt.x;
    o.y = (h.y - mean) * inv * g.y + bt.y;
    o.z = (h.z - mean) * inv * g.z + bt.z;
    o.w = (h.w - mean) * inv * g.w + bt.w;
    *(float4*)(out + ((size_t)(b * NN + row)) * DD + lane * 4) = o;
}

extern "C" void kernel_launch(void* const* d_in, const int* in_sizes, int n_in,
                              void* d_out, int out_size, void* d_ws, size_t ws_size,
                              hipStream_t stream) {
    const float* x     = (const float*)d_in[0];
    const float* c     = (const float*)d_in[1];
    const float* mask  = (const float*)d_in[2];
    const float* Wq    = (const float*)d_in[3];
    const float* bq    = (const float*)d_in[4];
    const float* Wk    = (const float*)d_in[5];
    const float* Wr    = (const float*)d_in[6];
    const float* Wv    = (const float*)d_in[7];
    const float* bv    = (const float*)d_in[8];
    const float* gamma = (const float*)d_in[9];
    const float* beta  = (const float*)d_in[10];
    float* out = (float*)d_out;

    float* ws    = (float*)d_ws;
    float* qs    = ws;                      // B*N = 2048 floats
    float* ksbuf = ws + BB * NN;            // B*M = 2048 floats
    float* vbuf  = ws + BB * NN + BB * MM;  // B*M*D = 524288 floats

    k_proj<<<512, 256, 0, stream>>>(x, c, Wq, bq, Wk, Wr, Wv, bv, qs, ksbuf, vbuf);
    k_main<<<(BB * NN) / NT2, 256, 0, stream>>>(x, mask, qs, ksbuf, vbuf, gamma, beta, out);
}

// Round 3
// 44.286 us; speedup vs baseline: 2.3947x; 1.2064x over previous
//
#include <hip/hip_runtime.h>
#include <math.h>

// Problem sizes (fixed): B=4, N=512, M=512, D=256
#define BB 4
#define NN 512
#define MM 512
#define DD 256

typedef short  s16x8 __attribute__((ext_vector_type(8)));
typedef __bf16 bf16x8 __attribute__((ext_vector_type(8)));
typedef float  f32x4 __attribute__((ext_vector_type(4)));
typedef unsigned short u16x4 __attribute__((ext_vector_type(4)));

static __device__ __forceinline__ f32x4 mfma16(s16x8 a, s16x8 b, f32x4 c) {
    return __builtin_amdgcn_mfma_f32_16x16x32_bf16(
        __builtin_bit_cast(bf16x8, a), __builtin_bit_cast(bf16x8, b), c, 0, 0, 0);
}

// f32 -> bf16 round-to-nearest-even (no NaN in this data)
static __device__ __forceinline__ unsigned short f2b(float f) {
    union { float f; unsigned u; } v; v.f = f;
    unsigned r = v.u + 0x7FFFu + ((v.u >> 16) & 1u);
    return (unsigned short)(r >> 16);
}

// ---------------- kernel 1: f32 -> bf16 conversion of Wq, Wk, Wv, x, c ----
// float4 counts: Wq/Wk/Wv 16384 each, x/c 131072 each => 311296 total
__global__ __launch_bounds__(256) void k_convert(
    const float* __restrict__ Wq, const float* __restrict__ Wk,
    const float* __restrict__ Wv, const float* __restrict__ x,
    const float* __restrict__ c,
    unsigned short* __restrict__ wqb, unsigned short* __restrict__ wkb,
    unsigned short* __restrict__ wvb, unsigned short* __restrict__ xb,
    unsigned short* __restrict__ cb)
{
    const int idx = blockIdx.x * 256 + threadIdx.x;
    const float* src; unsigned short* dst; int off;
    if      (idx <  16384) { src = Wq; dst = wqb; off = idx; }
    else if (idx <  32768) { src = Wk; dst = wkb; off = idx - 16384; }
    else if (idx <  49152) { src = Wv; dst = wvb; off = idx - 32768; }
    else if (idx < 180224) { src = x;  dst = xb;  off = idx - 49152; }
    else                   { src = c;  dst = cb;  off = idx - 180224; }
    const float4 v = ((const float4*)src)[off];
    u16x4 o;
    o.x = f2b(v.x); o.y = f2b(v.y); o.z = f2b(v.z); o.w = f2b(v.w);
    ((u16x4*)dst)[off] = o;
}

// ---------------- kernel 2: MFMA projections ------------------------------
// blocks [0,128):  qs[row0..row0+16) from x
// blocks [128,256): ks + vT from c
// Block: 256 thr = 4 waves; wave w covers e-cols [w*64, w*64+64) (4 n-tiles).
// 16 output rows per block, K = 256 (8 MFMA k-steps).
__global__ __launch_bounds__(256) void k_proj(
    const unsigned short* __restrict__ xb, const unsigned short* __restrict__ cb,
    const unsigned short* __restrict__ wqb, const unsigned short* __restrict__ wkb,
    const unsigned short* __restrict__ wvb,
    const float* __restrict__ bq, const float* __restrict__ Wr,
    const float* __restrict__ bv,
    float* __restrict__ qs, float* __restrict__ ks,
    unsigned short* __restrict__ vT)
{
    __shared__ float red[4][16];
    const int tid  = threadIdx.x;
    const int lane = tid & 63, w = tid >> 6;
    const int li   = lane & 15, g = lane >> 4;
    const bool isk = blockIdx.x >= 128;
    const int row0 = (blockIdx.x & 127) << 4;

    // A fragments: lane supplies A[i=li][k=g*8+t] for each k-step
    const unsigned short* src = isk ? cb : xb;
    const unsigned short* ap = src + (size_t)(row0 + li) * DD + g * 8;
    s16x8 af[8];
    #pragma unroll
    for (int kk = 0; kk < 8; ++kk) af[kk] = *(const s16x8*)(ap + kk * 32);

    const int e_base = w * 64 + li;

    if (!isk) {
        f32x4 acc[4];
        const unsigned short* bp[4];
        #pragma unroll
        for (int nt = 0; nt < 4; ++nt) {
            acc[nt] = (f32x4){0.f, 0.f, 0.f, 0.f};
            bp[nt] = wqb + (size_t)(e_base + nt * 16) * DD + g * 8;
        }
        #pragma unroll
        for (int kk = 0; kk < 8; ++kk)
            #pragma unroll
            for (int nt = 0; nt < 4; ++nt)
                acc[nt] = mfma16(af[kk], *(const s16x8*)(bp[nt] + kk * 32), acc[nt]);

        float p[4] = {0.f, 0.f, 0.f, 0.f};
        #pragma unroll
        for (int nt = 0; nt < 4; ++nt) {
            const int e = e_base + nt * 16;
            const float bqe = bq[e], wre = Wr[e];
            #pragma unroll
            for (int r = 0; r < 4; ++r)
                p[r] += wre * tanhf(acc[nt][r] + bqe);
        }
        #pragma unroll
        for (int r = 0; r < 4; ++r) {
            p[r] += __shfl_xor(p[r], 1);
            p[r] += __shfl_xor(p[r], 2);
            p[r] += __shfl_xor(p[r], 4);
            p[r] += __shfl_xor(p[r], 8);
        }
        if (li == 0) {
            #pragma unroll
            for (int r = 0; r < 4; ++r) red[w][g * 4 + r] = p[r];
        }
        __syncthreads();
        if (tid < 16)
            qs[row0 + tid] = red[0][tid] + red[1][tid] + red[2][tid] + red[3][tid];
    } else {
        f32x4 ak[4], av[4];
        const unsigned short* bpk[4];
        const unsigned short* bpv[4];
        #pragma unroll
        for (int nt = 0; nt < 4; ++nt) {
            ak[nt] = (f32x4){0.f, 0.f, 0.f, 0.f};
            av[nt] = (f32x4){0.f, 0.f, 0.f, 0.f};
            bpk[nt] = wkb + (size_t)(e_base + nt * 16) * DD + g * 8;
            bpv[nt] = wvb + (size_t)(e_base + nt * 16) * DD + g * 8;
        }
        #pragma unroll
        for (int kk = 0; kk < 8; ++kk)
            #pragma unroll
            for (int nt = 0; nt < 4; ++nt) {
                ak[nt] = mfma16(af[kk], *(const s16x8*)(bpk[nt] + kk * 32), ak[nt]);
                av[nt] = mfma16(af[kk], *(const s16x8*)(bpv[nt] + kk * 32), av[nt]);
            }

        // v epilogue: vT[b][e][m] bf16; lane holds rows m0+4g+r for col e
        const int b  = row0 >> 9;
        const int m0 = row0 & 511;
        unsigned short* vTb = vT + (size_t)b * (DD * MM);
        #pragma unroll
        for (int nt = 0; nt < 4; ++nt) {
            const int e = e_base + nt * 16;
            const float bve = bv[e];
            u16x4 o;
            #pragma unroll
            for (int r = 0; r < 4; ++r)
                o[r] = f2b((av[nt][r] + bve) * 0.0625f);  // 1/sqrt(256)
            *(u16x4*)(vTb + (size_t)e * MM + m0 + g * 4) = o;
        }

        // ks epilogue (no bias)
        float p[4] = {0.f, 0.f, 0.f, 0.f};
        #pragma unroll
        for (int nt = 0; nt < 4; ++nt) {
            const int e = e_base + nt * 16;
            const float wre = Wr[e];
            #pragma unroll
            for (int r = 0; r < 4; ++r)
                p[r] += wre * tanhf(ak[nt][r]);
        }
        #pragma unroll
        for (int r = 0; r < 4; ++r) {
            p[r] += __shfl_xor(p[r], 1);
            p[r] += __shfl_xor(p[r], 2);
            p[r] += __shfl_xor(p[r], 4);
            p[r] += __shfl_xor(p[r], 8);
        }
        if (li == 0) {
            #pragma unroll
            for (int r = 0; r < 4; ++r) red[w][g * 4 + r] = p[r];
        }
        __syncthreads();
        if (tid < 16)
            ks[row0 + tid] = red[0][tid] + red[1][tid] + red[2][tid] + red[3][tid];
    }
}

// ---------------- kernel 3: scores + PV (MFMA) + residual + LayerNorm -----
// 128 blocks x 16 n-rows. LDS w tile [16][512] bf16, XOR-swizzled
// (byte ^= (row&7)<<4) to kill the 1KB-row bank conflict on ds_read_b128.
__global__ __launch_bounds__(256) void k_main(
    const float* __restrict__ x, const float* __restrict__ mask,
    const float* __restrict__ qs, const float* __restrict__ ks,
    const unsigned short* __restrict__ vT,
    const float* __restrict__ gamma, const float* __restrict__ beta,
    float* __restrict__ out)
{
    __shared__ unsigned short w_lds[16][512];   // 16 KB
    __shared__ float ksm[MM];                   // 2 KB
    __shared__ float h_lds[16][260];            // 16.6 KB (stride 260 breaks conflicts)
    const int tid  = threadIdx.x;
    const int lane = tid & 63, w = tid >> 6;
    const int li   = lane & 15, g = lane >> 4;
    const int n0g  = blockIdx.x << 4;           // global n-row (b*512 + n)
    const int b    = n0g >> 9;

    ksm[tid]       = ks[(b << 9) + tid];
    ksm[tid + 256] = ks[(b << 9) + 256 + tid];
    __syncthreads();

    // scores -> bf16 swizzled LDS
    const float* __restrict__ mrow = mask + (size_t)n0g * MM;
    char* wbase = (char*)w_lds;
    #pragma unroll
    for (int it = 0; it < 32; ++it) {
        const int i = it >> 1;
        const int m = ((it & 1) << 8) + tid;
        const float qv = qs[n0g + i];
        float s = tanhf(qv + ksm[m]);
        s = fmaxf(s, 0.f) * mrow[(size_t)i * MM + m];
        *(unsigned short*)(wbase + (i << 10) + (((m << 1)) ^ ((i & 7) << 4))) = f2b(s);
    }
    __syncthreads();

    // PV: wave w covers e-cols [w*64, w*64+64), K = 512 (16 k-steps)
    f32x4 acc[4];
    const unsigned short* vp[4];
    #pragma unroll
    for (int nt = 0; nt < 4; ++nt) {
        acc[nt] = (f32x4){0.f, 0.f, 0.f, 0.f};
        vp[nt] = vT + (size_t)b * (DD * MM)
                    + (size_t)(w * 64 + nt * 16 + li) * MM + g * 8;
    }
    const char* arow = wbase + (li << 10);
    const int aswz = (li & 7) << 4;
    #pragma unroll
    for (int kk = 0; kk < 16; ++kk) {
        const s16x8 a = *(const s16x8*)(arow + (((kk << 6) + (g << 4)) ^ aswz));
        #pragma unroll
        for (int nt = 0; nt < 4; ++nt)
            acc[nt] = mfma16(a, *(const s16x8*)(vp[nt] + kk * 32), acc[nt]);
    }

    // scatter partial h into LDS: lane holds rows 4g+r, col e
    #pragma unroll
    for (int nt = 0; nt < 4; ++nt) {
        const int e = w * 64 + nt * 16 + li;
        #pragma unroll
        for (int r = 0; r < 4; ++r)
            h_lds[g * 4 + r][e] = acc[nt][r];
    }
    __syncthreads();

    // LN: wave w owns rows w*4 .. w*4+3; lane owns 4 contiguous d
    const float4 gm = ((const float4*)gamma)[lane];
    const float4 bt = ((const float4*)beta)[lane];
    #pragma unroll
    for (int rr = 0; rr < 4; ++rr) {
        const int row = w * 4 + rr;
        const float4 hv = *(const float4*)&h_lds[row][lane << 2];
        const float4 xv = *(const float4*)(x + ((size_t)(n0g + row)) * DD + (lane << 2));
        float4 h;
        h.x = xv.x + hv.x; h.y = xv.y + hv.y;
        h.z = xv.z + hv.z; h.w = xv.w + hv.w;
        float s  = h.x + h.y + h.z + h.w;
        float s2 = h.x * h.x + h.y * h.y + h.z * h.z + h.w * h.w;
        #pragma unroll
        for (int off = 32; off; off >>= 1) {
            s  += __shfl_xor(s, off);
            s2 += __shfl_xor(s2, off);
        }
        const float mean = s * (1.0f / DD);
        const float var  = s2 * (1.0f / DD) - mean * mean;
        const float inv  = rsqrtf(var + 1e-5f);
        float4 o;
        o.x = (h.x - mean) * inv * gm.x + bt.x;
        o.y = (h.y - mean) * inv * gm.y + bt.y;
        o.z = (h.z - mean) * inv * gm.z + bt.z;
        o.w = (h.w - mean) * inv * gm.w + bt.w;
        *(float4*)(out + ((size_t)(n0g + row)) * DD + (lane << 2)) = o;
    }
}

extern "C" void kernel_launch(void* const* d_in, const int* in_sizes, int n_in,
                              void* d_out, int out_size, void* d_ws, size_t ws_size,
                              hipStream_t stream) {
    const float* x     = (const float*)d_in[0];
    const float* c     = (const float*)d_in[1];
    const float* mask  = (const float*)d_in[2];
    const float* Wq    = (const float*)d_in[3];
    const float* bq    = (const float*)d_in[4];
    const float* Wk    = (const float*)d_in[5];
    const float* Wr    = (const float*)d_in[6];
    const float* Wv    = (const float*)d_in[7];
    const float* bv    = (const float*)d_in[8];
    const float* gamma = (const float*)d_in[9];
    const float* beta  = (const float*)d_in[10];
    float* out = (float*)d_out;

    float* ws = (float*)d_ws;
    float* qs  = ws;                         // 2048 f32
    float* ksb = ws + 2048;                  // 2048 f32
    unsigned short* ub  = (unsigned short*)(ws + 4096);
    unsigned short* wqb = ub;                // 65536 bf16
    unsigned short* wkb = wqb + 65536;
    unsigned short* wvb = wkb + 65536;
    unsigned short* xb  = wvb + 65536;       // 524288 bf16
    unsigned short* cb  = xb + 524288;
    unsigned short* vT  = cb + 524288;       // 524288 bf16 ([b][e][m])

    k_convert<<<1216, 256, 0, stream>>>(Wq, Wk, Wv, x, c, wqb, wkb, wvb, xb, cb);
    k_proj   <<<256, 256, 0, stream>>>(xb, cb, wqb, wkb, wvb, bq, Wr, bv, qs, ksb, vT);
    k_main   <<<128, 256, 0, stream>>>(x, mask, qs, ksb, vT, gamma, beta, out);
}